// Round 11
// baseline (2012.792 us; speedup 1.0000x reference)
//
#include <hip/hip_runtime.h>

#define T_ 512
#define B_ 256
#define H_ 512
#define NBINS 4112  // 514 buckets x 8 subs (pooled: bin = bk*8 + (b>>5))
typedef __bf16 bf16_t;
typedef __bf16 bf16x8 __attribute__((ext_vector_type(8)));
typedef float f32x4 __attribute__((ext_vector_type(4)));

// ---------------------------------------------------------------------------
__device__ __forceinline__ float bf2f(unsigned short u) {
  unsigned x = ((unsigned)u) << 16; float f; __builtin_memcpy(&f, &x, 4); return f;
}
__device__ __forceinline__ bf16x8 pack2(f32x4 a, f32x4 b) {
  bf16x8 w;
#pragma unroll
  for (int i = 0; i < 4; ++i) { w[i] = (bf16_t)a[i]; w[i + 4] = (bf16_t)b[i]; }
  return w;
}
__device__ __forceinline__ void st_sc1(float* p, float v) {
  asm volatile("global_store_dword %0, %1, off sc0 sc1" :: "v"(p), "v"(v) : "memory");
}
__device__ __forceinline__ void st_flag(int* p, int v) {
  asm volatile("global_store_dword %0, %1, off sc0 sc1" :: "v"(p), "v"(v) : "memory");
}
__device__ __forceinline__ int ld_flag(const int* p) {
  int v;
  asm volatile("global_load_dword %0, %1, off sc0 sc1\n\ts_waitcnt vmcnt(0)"
               : "=v"(v) : "v"(p) : "memory");
  return v;
}
// 8 device-coherent 16B loads; wait INSIDE the asm (r5 lesson: issue/wait split
// across asm blocks corrupts pending regs via spills).
__device__ __forceinline__ void ld8_sc1(const float* p0, const float* p1,
                                        const float* p2, const float* p3,
                                        const float* p4, const float* p5,
                                        const float* p6, const float* p7,
                                        f32x4& v0, f32x4& v1, f32x4& v2, f32x4& v3,
                                        f32x4& v4, f32x4& v5, f32x4& v6, f32x4& v7) {
  asm volatile(
      "global_load_dwordx4 %0, %8, off sc0 sc1\n\t"
      "global_load_dwordx4 %1, %9, off sc0 sc1\n\t"
      "global_load_dwordx4 %2, %10, off sc0 sc1\n\t"
      "global_load_dwordx4 %3, %11, off sc0 sc1\n\t"
      "global_load_dwordx4 %4, %12, off sc0 sc1\n\t"
      "global_load_dwordx4 %5, %13, off sc0 sc1\n\t"
      "global_load_dwordx4 %6, %14, off sc0 sc1\n\t"
      "global_load_dwordx4 %7, %15, off sc0 sc1\n\t"
      "s_waitcnt vmcnt(0)"
      : "=&v"(v0), "=&v"(v1), "=&v"(v2), "=&v"(v3),
        "=&v"(v4), "=&v"(v5), "=&v"(v6), "=&v"(v7)
      : "v"(p0), "v"(p1), "v"(p2), "v"(p3), "v"(p4), "v"(p5), "v"(p6), "v"(p7)
      : "memory");
}
__device__ __forceinline__ float sigm(float x) { return 1.f / (1.f + __expf(-x)); }
__device__ __forceinline__ float tanh_(float a) { return 1.f - 2.f / (__expf(2.f * a) + 1.f); }

// ---------------------------------------------------------------------------
__global__ __launch_bounds__(512) void zero_meta(int* __restrict__ flags,
                                                 int* __restrict__ farr,
                                                 int* __restrict__ rel) {
  int i = threadIdx.x;
  if (i < 4) flags[i] = 0;
  if (i < 256) farr[i] = 0;
  if (i == 0) rel[0] = 0;
}

__global__ __launch_bounds__(256) void detect_resets(const void* __restrict__ rst,
                                                     int n, int* __restrict__ flags) {
  const int* pi = (const int*)rst;
  const float* pf = (const float*)rst;
  int a = 0, bq = 0, c = 0;
  int nq = n >> 2;
  for (int i = blockIdx.x * 256 + threadIdx.x; i < nq; i += gridDim.x * 256) {
    int v = pi[i];
    if (v != 0 && v != 1) a = 1;
    float f = pf[i];
    if (!(f == 0.0f || f == 1.0f)) bq = 1;
    if ((i & 1) && v != 0) c = 1;
  }
  if (a) atomicOr(&flags[0], 1);
  if (bq) atomicOr(&flags[1], 1);
  if (c) atomicOr(&flags[2], 1);
}

__global__ __launch_bounds__(256) void convert_resets(const void* __restrict__ rst,
                                                      const int* __restrict__ flags,
                                                      unsigned char* __restrict__ r8,
                                                      int n) {
  const int* pi = (const int*)rst;
  const float* pf = (const float*)rst;
  int mode;
  if (flags[0] == 0) mode = flags[2] ? 0 : 3;  // int32 / int64
  else if (flags[1] == 0) mode = 1;            // f32
  else mode = 2;                               // bytes
  for (int i = blockIdx.x * 256 + threadIdx.x; i < n; i += gridDim.x * 256) {
    unsigned char v;
    if (mode == 0)      v = (unsigned char)(pi[i] != 0);
    else if (mode == 3) v = (unsigned char)(pi[2 * i] != 0);
    else if (mode == 1) v = (unsigned char)(pf[i] != 0.0f);
    else                v = ((const unsigned char*)rst)[i] ? 1 : 0;
    r8[i] = v;
  }
}

// Wc[koct 0..127][n 0..1535][8 bf16]: koct<64 -> Wi[koct*8+e][n]; else Wh.
__global__ __launch_bounds__(256) void build_wc(const float* __restrict__ Wi,
                                                const float* __restrict__ Wh,
                                                bf16_t* __restrict__ Wc) {
  int id = blockIdx.x * 256 + threadIdx.x;  // 0..196607
  int koct = id / 1536, n = id % 1536;
  const float* src = (koct < 64) ? Wi : Wh;
  int kk = (koct & 63) * 8;
  bf16x8 w;
#pragma unroll
  for (int e = 0; e < 8; ++e) w[e] = (bf16_t)src[(size_t)(kk + e) * 1536 + n];
  *(bf16x8*)(Wc + (size_t)id * 8) = w;
}

// bucket: p==0 -> (t==0 && !reset) ? 1 : 0; else p+1.  Pooled bin = bk*8+(b>>5).
__device__ __forceinline__ int bucket_of(int t, int rs, int& p) {
  p = (t == 0 || rs) ? 0 : p + 1;
  return (p > 0) ? (p + 1) : ((t == 0 && !rs) ? 1 : 0);
}

// Merged count + scan + scatter. 1 block x 1024 threads, 64KB dyn LDS.
__global__ __launch_bounds__(1024) void bins_kernel(const unsigned char* __restrict__ r8,
                                                    int* __restrict__ cur,
                                                    unsigned int* __restrict__ elem) {
  extern __shared__ int sm[];  // 2 x 8192
  int* s0 = sm;
  int* s1 = sm + 8192;
  const int tid = threadIdx.x;
  for (int i = tid; i < 8192; i += 1024) s0[i] = 0;
  __syncthreads();
  if (tid < 256) {
    int b = tid, sub = b >> 5, p = 0;
    for (int t = 0; t < T_; ++t) {
      int bk = bucket_of(t, r8[t * B_ + b], p);
      atomicAdd(&s0[bk * 8 + sub], 1);
    }
  }
  __syncthreads();
  int* a = s0;
  int* bb = s1;
  for (int d = 1; d < 8192; d <<= 1) {
    for (int i = tid; i < 8192; i += 1024) bb[i] = a[i] + ((i >= d) ? a[i - d] : 0);
    __syncthreads();
    int* t = a; a = bb; bb = t;
  }
  for (int i = tid; i <= NBINS; i += 1024) cur[i] = (i == 0) ? 0 : a[i - 1];
  for (int i = tid; i < 8192; i += 1024)
    bb[i] = (i == 0) ? 0 : ((i <= NBINS) ? a[i - 1] : 0);
  __syncthreads();
  if (tid < 256) {
    int b = tid, sub = b >> 5, p = 0;
    for (int t = 0; t < T_; ++t) {
      int bk = bucket_of(t, r8[t * B_ + b], p);
      int pos = atomicAdd(&bb[bk * 8 + sub], 1);
      elem[pos] = (unsigned)(t * B_ + b);
    }
  }
}

// ---------------------------------------------------------------------------
// 3-gate MFMA core, K=512 (x-only kernel).
// ---------------------------------------------------------------------------
template <int NRGC, int LDB>
__device__ __forceinline__ void mm3(const char* lds, const char* W, int q,
                                    int rgb, int span, int nrgd, int am, int aq,
                                    f32x4 (&acc)[3][NRGC]) {
  const char* Bp = W + (size_t)(q * 16 + am) * 16;
#pragma unroll
  for (int ks = 0; ks < 16; ++ks) {
    const int koct = ks * 4 + aq;
    const char* bb = Bp + (size_t)koct * 24576;
    bf16x8 b0 = *(const bf16x8*)(bb);
    bf16x8 b1 = *(const bf16x8*)(bb + 8192);
    bf16x8 b2 = *(const bf16x8*)(bb + 16384);
#pragma unroll
    for (int rg = 0; rg < NRGC; ++rg) {
      if (rg >= rgb && rg < rgb + span && rg < nrgd) {
        const int ar = rg * 16 + am;
        bf16x8 af = *(const bf16x8*)(lds + (size_t)ar * LDB +
                                     ((koct * 16) ^ ((ar & 7) << 4)));
        acc[0][rg] = __builtin_amdgcn_mfma_f32_16x16x32_bf16(af, b0, acc[0][rg], 0, 0, 0);
        acc[1][rg] = __builtin_amdgcn_mfma_f32_16x16x32_bf16(af, b1, acc[1][rg], 0, 0, 0);
        acc[2][rg] = __builtin_amdgcn_mfma_f32_16x16x32_bf16(af, b2, acc[2][rg], 0, 0, 0);
      }
    }
  }
}

// 4-acc K=1024 core (64-row scan path, r6-proven).
template <int NKS, int NRGC, int LDB>
__device__ __forceinline__ void mm_block(const char* lds, const char* W, int q,
                                         int rgb, int span, int nrgd, int am, int aq,
                                         f32x4 (&acc)[4][NRGC]) {
  const char* Bp = W + (size_t)(q * 16 + am) * 16;
#pragma unroll
  for (int ks = 0; ks < NKS; ++ks) {
    const int koct = ks * 4 + aq;
    const char* bb = Bp + (size_t)koct * 24576;
    bf16x8 b0 = *(const bf16x8*)(bb);
    bf16x8 b1 = *(const bf16x8*)(bb + 8192);
    bf16x8 b2 = *(const bf16x8*)(bb + 16384);
#pragma unroll
    for (int rg = 0; rg < NRGC; ++rg) {
      if (rg >= rgb && rg < rgb + span && rg < nrgd) {
        const int ar = rg * 16 + am;
        bf16x8 af = *(const bf16x8*)(lds + (size_t)ar * LDB +
                                     ((koct * 16) ^ ((ar & 7) << 4)));
        acc[0][rg] = __builtin_amdgcn_mfma_f32_16x16x32_bf16(af, b0, acc[0][rg], 0, 0, 0);
        acc[1][rg] = __builtin_amdgcn_mfma_f32_16x16x32_bf16(af, b1, acc[1][rg], 0, 0, 0);
        if (ks < 16)
          acc[2][rg] = __builtin_amdgcn_mfma_f32_16x16x32_bf16(af, b2, acc[2][rg], 0, 0, 0);
        else
          acc[3][rg] = __builtin_amdgcn_mfma_f32_16x16x32_bf16(af, b2, acc[3][rg], 0, 0, 0);
      }
    }
  }
}

// 128-row core: x A-frags from global xb (bf16), h A-frags from LDS (LDB=1024).
__device__ __forceinline__ void mm128(const char* lds, const bf16_t* const (&xp)[8],
                                      const char* W, int q, int am, int aq,
                                      f32x4 (&acc)[4][8]) {
  const char* Bp = W + (size_t)(q * 16 + am) * 16;
#pragma unroll 4
  for (int ks = 0; ks < 16; ++ks) {  // x half: koct 0..63
    const int koct = ks * 4 + aq;
    const char* bb = Bp + (size_t)koct * 24576;
    bf16x8 b0 = *(const bf16x8*)(bb);
    bf16x8 b1 = *(const bf16x8*)(bb + 8192);
    bf16x8 b2 = *(const bf16x8*)(bb + 16384);
#pragma unroll
    for (int rg = 0; rg < 8; ++rg) {
      bf16x8 af = *(const bf16x8*)(xp[rg] + koct * 8);
      acc[0][rg] = __builtin_amdgcn_mfma_f32_16x16x32_bf16(af, b0, acc[0][rg], 0, 0, 0);
      acc[1][rg] = __builtin_amdgcn_mfma_f32_16x16x32_bf16(af, b1, acc[1][rg], 0, 0, 0);
      acc[2][rg] = __builtin_amdgcn_mfma_f32_16x16x32_bf16(af, b2, acc[2][rg], 0, 0, 0);
    }
  }
#pragma unroll 4
  for (int ks = 16; ks < 32; ++ks) {  // h half: koct 64..127, A from LDS
    const int koct = ks * 4 + aq;
    const char* bb = Bp + (size_t)koct * 24576;
    bf16x8 b0 = *(const bf16x8*)(bb);
    bf16x8 b1 = *(const bf16x8*)(bb + 8192);
    bf16x8 b2 = *(const bf16x8*)(bb + 16384);
#pragma unroll
    for (int rg = 0; rg < 8; ++rg) {
      const int ar = rg * 16 + am;
      bf16x8 af = *(const bf16x8*)(lds + (size_t)ar * 1024 +
                                   (((koct - 64) * 16) ^ ((ar & 7) << 4)));
      acc[0][rg] = __builtin_amdgcn_mfma_f32_16x16x32_bf16(af, b0, acc[0][rg], 0, 0, 0);
      acc[1][rg] = __builtin_amdgcn_mfma_f32_16x16x32_bf16(af, b1, acc[1][rg], 0, 0, 0);
      acc[3][rg] = __builtin_amdgcn_mfma_f32_16x16x32_bf16(af, b2, acc[3][rg], 0, 0, 0);
    }
  }
}

// ---------------------------------------------------------------------------
// x-only GEMM over ALL 131072 rows: finishes reset rows (h==0 -> out);
// also emits xb (bf16 copy of ins) for the pool's 128-row mode.
// ---------------------------------------------------------------------------
__global__ __launch_bounds__(512) void xonly_gemm(
    const float* __restrict__ ins, const bf16_t* __restrict__ Wic,
    const float* __restrict__ bi, const float* __restrict__ bhn,
    const unsigned char* __restrict__ r8, bf16_t* __restrict__ xb,
    float* __restrict__ out) {
  extern __shared__ char lds[];
  const int u = blockIdx.x;
  const int tid = threadIdx.x, lane = tid & 63, w = tid >> 6;
  const int am = lane & 15, aq = lane >> 4;
  {  // stage 128 rows x 512 f32 -> bf16, LDB=1024, XOR-swizzled (+ xb emit)
    const int tr = tid >> 2, tl = tid & 3;
    const int row = u * 128 + tr;
    const float* xs = ins + (size_t)row * 512;
    const int swz = (tr & 7) << 4;
    char* lrp = lds + tr * 1024;
#pragma unroll 4
    for (int s2 = 0; s2 < 16; ++s2) {
      const int ko = tl + 4 * s2;
      f32x4 a0 = __builtin_nontemporal_load((const f32x4*)(xs + ko * 8));
      f32x4 a1 = __builtin_nontemporal_load((const f32x4*)(xs + ko * 8 + 4));
      bf16x8 wv = pack2(a0, a1);
      *(bf16x8*)(lrp + ((ko * 16) ^ swz)) = wv;
      if (xb) __builtin_nontemporal_store(wv, (bf16x8*)(xb + (size_t)row * 512 + ko * 8));
    }
  }
  __syncthreads();
#pragma unroll 1
  for (int s = 0; s < 4; ++s) {
    const int q = w + 8 * s;
    f32x4 acc[3][8];
#pragma unroll
    for (int gg = 0; gg < 3; ++gg)
#pragma unroll
      for (int r = 0; r < 8; ++r) acc[gg][r] = (f32x4){0.f, 0.f, 0.f, 0.f};
    mm3<8, 1024>(lds, (const char*)Wic, q, 0, 8, 8, am, aq, acc);
    const int j = q * 16 + am;
    const float bir = bi[j], biz = bi[512 + j], bin = bi[1024 + j], bh = bhn[j];
#pragma unroll
    for (int rg = 0; rg < 8; ++rg) {
#pragma unroll
      for (int qq = 0; qq < 4; ++qq) {
        const int e = u * 128 + rg * 16 + aq * 4 + qq;
        if (r8[e]) {  // reset: h==0, finished here
          float r = sigm(acc[0][rg][qq] + bir);
          float z = sigm(acc[1][rg][qq] + biz);
          float n = tanh_(acc[2][rg][qq] + bin + r * bh);
          float v = (1.f - z) * n;
          float* op = out + (size_t)e * 512 + j;
          if (e >= (T_ - 1) * B_ || r8[e + B_]) __builtin_nontemporal_store(v, op);
          else st_sc1(op, v);
        }
      }
    }
  }
}

// ---------------------------------------------------------------------------
// Pooled cooperative phase sweep. Big buckets (cnt>=8192): 128-row tiles,
// h-only LDS (128KB), x from xb (L2-cached) -> half the Wc stream per element.
// Small buckets: proven 64-row K=1024 path. Flag barrier: block stores
// farr[bid]=done (sc1); block 0 gathers 256 flags wave-wide, stores release.
// ---------------------------------------------------------------------------
__global__ __launch_bounds__(512) void gru_pool(
    const float* __restrict__ ins, const float* __restrict__ h0,
    const bf16_t* __restrict__ Wc, const float* __restrict__ bi,
    const float* __restrict__ bhn, const unsigned char* __restrict__ r8,
    const unsigned int* __restrict__ elem, const int* __restrict__ cur,
    const bf16_t* __restrict__ xb, int use128, int* __restrict__ farr,
    int* __restrict__ rel, float* __restrict__ out) {
  extern __shared__ char lds[];
  const int tid = threadIdx.x, lane = tid & 63, w = tid >> 6;
  const int am = lane & 15, aq = lane >> 4;
  const int nbg = gridDim.x, bg = blockIdx.x;
  int done = 0;

  for (int it = 1; it <= 513; ++it) {
    const int beg = cur[it * 8];
    const int cnt = cur[(it + 1) * 8] - beg;
    if (it >= 2 && cnt == 0) break;
    if (cnt >= 8192 && use128) {
      // ============== 128-row mode ==============
      const int ntiles = (cnt + 127) >> 7;
      int lg = 0;
      while (lg < 2 && (ntiles << lg) < nbg) ++lg;
      const int nitems = ntiles << lg;
      const int nsp = 4 >> lg;  // s-passes per item
      for (int i = bg; i < nitems; i += nbg) {
        const int u = i >> lg, sc = i & ((1 << lg) - 1);
        __syncthreads();
        {  // stage h only: 128 rows x 512 f32 -> bf16 (LDB=1024)
          const int tr = tid >> 2, tl = tid & 3;
          const int row = u * 128 + tr;
          const float* ph = nullptr;
          if (row < cnt) {
            const unsigned e = elem[beg + row];
            ph = (e < 256) ? (h0 + (size_t)e * 512) : (out + ((size_t)e - 256) * 512);
          }
          const int swz = (tr & 7) << 4;
          char* lrp = lds + tr * 1024;
          if (ph) {
#pragma unroll 1
            for (int hb = 0; hb < 4; ++hb) {
              f32x4 hv[8];
              const float* hp[8];
#pragma unroll
              for (int s2 = 0; s2 < 4; ++s2) {
                const int ko = tl * 16 + hb * 4 + s2;
                hp[2 * s2] = ph + ko * 8;
                hp[2 * s2 + 1] = ph + ko * 8 + 4;
              }
              ld8_sc1(hp[0], hp[1], hp[2], hp[3], hp[4], hp[5], hp[6], hp[7],
                      hv[0], hv[1], hv[2], hv[3], hv[4], hv[5], hv[6], hv[7]);
#pragma unroll
              for (int s2 = 0; s2 < 4; ++s2) {
                const int ko = tl * 16 + hb * 4 + s2;
                *(bf16x8*)(lrp + ((ko * 16) ^ swz)) = pack2(hv[2 * s2], hv[2 * s2 + 1]);
              }
            }
          } else {
#pragma unroll
            for (int s2 = 0; s2 < 16; ++s2) {
              const int ko = tl * 16 + s2;
              bf16x8 wv;
#pragma unroll
              for (int z = 0; z < 8; ++z) wv[z] = (bf16_t)0.f;
              *(bf16x8*)(lrp + ((ko * 16) ^ swz)) = wv;
            }
          }
        }
        __syncthreads();
        // per-lane xb row pointers (clamped)
        const bf16_t* xp[8];
#pragma unroll
        for (int rg = 0; rg < 8; ++rg) {
          int row = u * 128 + rg * 16 + am;
          int rc = (row < cnt) ? row : (cnt - 1);
          xp[rg] = xb + (size_t)elem[beg + rc] * 512;
        }
#pragma unroll 1
        for (int si = 0; si < nsp; ++si) {
          const int s = sc * nsp + si;
          const int q = w + 8 * s;
          f32x4 acc[4][8];
#pragma unroll
          for (int gg = 0; gg < 4; ++gg)
#pragma unroll
            for (int r = 0; r < 8; ++r) acc[gg][r] = (f32x4){0.f, 0.f, 0.f, 0.f};
          mm128(lds, xp, (const char*)Wc, q, am, aq, acc);
          const int j = q * 16 + am;
          const float bir = bi[j], biz = bi[512 + j], bin = bi[1024 + j], bh = bhn[j];
#pragma unroll
          for (int rg = 0; rg < 8; ++rg) {
#pragma unroll
            for (int qq = 0; qq < 4; ++qq) {
              const int lrow = rg * 16 + aq * 4 + qq;
              const int row = u * 128 + lrow;
              if (row < cnt) {
                const unsigned e = elem[beg + row];
                unsigned short hraw = *(const unsigned short*)(
                    lds + (size_t)lrow * 1024 +
                    (((j >> 3) * 16) ^ ((lrow & 7) << 4)) + (j & 7) * 2);
                float hp = bf2f(hraw);
                float r = sigm(acc[0][rg][qq] + bir);
                float z = sigm(acc[1][rg][qq] + biz);
                float n = tanh_(acc[2][rg][qq] + bin + r * (acc[3][rg][qq] + bh));
                float v = (1.f - z) * n + z * hp;
                float* op = out + (size_t)e * 512 + j;
                if (e >= (T_ - 1) * B_ || r8[e + B_]) *op = v;
                else st_sc1(op, v);
              }
            }
          }
        }
      }
    } else if (cnt > 0) {
      // ============== 64-row mode (r6-proven) ==============
      const int ntiles = (cnt + 63) >> 6;
      int lg = 0;
      while (lg < 4 && (ntiles << lg) < nbg) ++lg;
      const int nitems = ntiles << lg;
      const int Q = 32 >> lg;
      for (int i = bg; i < nitems; i += nbg) {
        const int u = i >> lg, jc = i & ((1 << lg) - 1);
        __syncthreads();
        {  // stage 64 rows x (512 x | 512 h); x nt-cached, h sc1 (waits inside)
          const int tr = tid >> 3, tl = tid & 7;
          const int row = u * 64 + tr;
          const float* xs = nullptr;
          const float* ph = nullptr;
          if (row < cnt) {
            const unsigned e = elem[beg + row];
            xs = ins + (size_t)e * 512;
            ph = (e < 256) ? (h0 + (size_t)e * 512) : (out + ((size_t)e - 256) * 512);
          }
          const int swz = (tr & 7) << 4;
          char* lrp = lds + tr * 2048;
#pragma unroll
          for (int s2 = 0; s2 < 8; ++s2) {
            const int ko = tl + 8 * s2;
            bf16x8 wv;
            if (xs) {
              f32x4 a0 = __builtin_nontemporal_load((const f32x4*)(xs + ko * 8));
              f32x4 a1 = __builtin_nontemporal_load((const f32x4*)(xs + ko * 8 + 4));
              wv = pack2(a0, a1);
            } else {
#pragma unroll
              for (int z = 0; z < 8; ++z) wv[z] = (bf16_t)0.f;
            }
            *(bf16x8*)(lrp + ((ko * 16) ^ swz)) = wv;
          }
          if (ph) {
#pragma unroll 1
            for (int hb = 0; hb < 2; ++hb) {
              f32x4 hv[8];
              const float* hp[8];
#pragma unroll
              for (int s2 = 0; s2 < 4; ++s2) {
                const int ko = tl + 8 * (8 + hb * 4 + s2);
                hp[2 * s2] = ph + (ko & 63) * 8;
                hp[2 * s2 + 1] = ph + (ko & 63) * 8 + 4;
              }
              ld8_sc1(hp[0], hp[1], hp[2], hp[3], hp[4], hp[5], hp[6], hp[7],
                      hv[0], hv[1], hv[2], hv[3], hv[4], hv[5], hv[6], hv[7]);
#pragma unroll
              for (int s2 = 0; s2 < 4; ++s2) {
                const int ko = tl + 8 * (8 + hb * 4 + s2);
                *(bf16x8*)(lrp + ((ko * 16) ^ swz)) = pack2(hv[2 * s2], hv[2 * s2 + 1]);
              }
            }
          } else {
#pragma unroll
            for (int s2 = 0; s2 < 8; ++s2) {
              const int ko = tl + 8 * (8 + s2);
              bf16x8 wv;
#pragma unroll
              for (int z = 0; z < 8; ++z) wv[z] = (bf16_t)0.f;
              *(bf16x8*)(lrp + ((ko * 16) ^ swz)) = wv;
            }
          }
        }
        __syncthreads();
        const int rem = cnt - u * 64;
        const int nrgd = ((rem < 64 ? rem : 64) + 15) >> 4;
        const int span = (Q >= 8) ? 4 : (Q >> 1);
        const int rgb = (Q >= 8) ? 0 : (w / Q) * span;
        const int nq = (Q >= 8) ? (Q >> 3) : 1;
#pragma unroll 1
        for (int s = 0; s < nq; ++s) {
          const int q = (Q >= 8) ? (jc * Q + w + 8 * s) : (jc * Q + (w & (Q - 1)));
          f32x4 acc[4][4];
#pragma unroll
          for (int gg = 0; gg < 4; ++gg)
#pragma unroll
            for (int r = 0; r < 4; ++r) acc[gg][r] = (f32x4){0.f, 0.f, 0.f, 0.f};
          mm_block<32, 4, 2048>(lds, (const char*)Wc, q, rgb, span, nrgd, am, aq, acc);
          const int j = q * 16 + am;
          const float bir = bi[j], biz = bi[512 + j], bin = bi[1024 + j], bh = bhn[j];
#pragma unroll
          for (int rg = 0; rg < 4; ++rg) {
            if (rg >= rgb && rg < rgb + span && rg < nrgd) {
#pragma unroll
              for (int qq = 0; qq < 4; ++qq) {
                const int lrow = rg * 16 + aq * 4 + qq;
                const int row = u * 64 + lrow;
                if (row < cnt) {
                  const unsigned e = elem[beg + row];
                  unsigned short hraw = *(const unsigned short*)(
                      lds + (size_t)lrow * 2048 +
                      (((64 + (j >> 3)) * 16) ^ ((lrow & 7) << 4)) + (j & 7) * 2);
                  float hp = bf2f(hraw);
                  float r = sigm(acc[0][rg][qq] + bir);
                  float z = sigm(acc[1][rg][qq] + biz);
                  float n = tanh_(acc[2][rg][qq] + bin + r * (acc[3][rg][qq] + bh));
                  float v = (1.f - z) * n + z * hp;
                  float* op = out + (size_t)e * 512 + j;
                  if (e >= (T_ - 1) * B_ || r8[e + B_]) *op = v;
                  else st_sc1(op, v);
                }
              }
            }
          }
        }
      }
    }
    // ---- flag barrier (no atomic RMW chain) ----
    __syncthreads();  // drains each wave's vmcnt -> block's out-stores in L3
    ++done;
    if (tid == 0) st_flag(&farr[bg], done);
    if (bg == 0) {
      for (;;) {
        int f = (tid < nbg) ? ld_flag(&farr[tid]) : done;
        if (__syncthreads_count(f >= done) == (int)blockDim.x) break;
        __builtin_amdgcn_s_sleep(1);
      }
      if (tid == 0) st_flag(rel, done);
    }
    if (tid == 0) {
      while (ld_flag(rel) < done) __builtin_amdgcn_s_sleep(1);
    }
    __syncthreads();
  }
}

// ---------------------------------------------------------------------------
extern "C" void kernel_launch(void* const* d_in, const int* in_sizes, int n_in,
                              void* d_out, int out_size, void* d_ws, size_t ws_size,
                              hipStream_t stream) {
  const float* h0  = (const float*)d_in[0];
  const float* ins = (const float*)d_in[1];
  const float* Wi  = (const float*)d_in[2];
  const float* bi  = (const float*)d_in[3];
  const float* Wh  = (const float*)d_in[4];
  const float* bhn = (const float*)d_in[5];
  const void*  rst = d_in[6];
  float* out = (float*)d_out;

  char* ws = (char*)d_ws;
  const size_t off_r8    = 0;         // 131072
  const size_t off_Wc    = 131072;    // 3145728
  const size_t off_flags = 3276800;   // 64
  const size_t off_farr  = 3276864;   // 1024
  const size_t off_rel   = 3277888;   // 64
  const size_t off_cur   = 3277952;   // 16512
  const size_t off_elem  = 3294464;   // 524288
  const size_t off_xb    = 3818752;   // 134217728
  const size_t need      = 3818752;
  const size_t need_xb   = off_xb + (size_t)131072 * 512 * 2;
  if (ws_size < need) return;  // loud failure
  const int use128 = (ws_size >= need_xb) ? 1 : 0;

  unsigned char* r8 = (unsigned char*)(ws + off_r8);
  bf16_t* Wc = (bf16_t*)(ws + off_Wc);
  int* flags = (int*)(ws + off_flags);
  int* farr = (int*)(ws + off_farr);
  int* rel = (int*)(ws + off_rel);
  int* cur = (int*)(ws + off_cur);
  unsigned int* elem = (unsigned int*)(ws + off_elem);
  bf16_t* xb = use128 ? (bf16_t*)(ws + off_xb) : nullptr;

  zero_meta<<<1, 512, 0, stream>>>(flags, farr, rel);
  detect_resets<<<64, 256, 0, stream>>>(rst, T_ * B_, flags);
  convert_resets<<<128, 256, 0, stream>>>(rst, flags, r8, T_ * B_);
  build_wc<<<768, 256, 0, stream>>>(Wi, Wh, Wc);
  (void)hipFuncSetAttribute((const void*)bins_kernel,
                            hipFuncAttributeMaxDynamicSharedMemorySize, 65536);
  bins_kernel<<<1, 1024, 65536, stream>>>(r8, cur, elem);

  (void)hipFuncSetAttribute((const void*)xonly_gemm,
                            hipFuncAttributeMaxDynamicSharedMemorySize, 131072);
  xonly_gemm<<<1024, 512, 131072, stream>>>(ins, Wc, bi, bhn, r8, xb, out);

  (void)hipFuncSetAttribute((const void*)gru_pool,
                            hipFuncAttributeMaxDynamicSharedMemorySize, 131072);
  void* args[] = {(void*)&ins, (void*)&h0, (void*)&Wc, (void*)&bi, (void*)&bhn,
                  (void*)&r8, (void*)&elem, (void*)&cur, (void*)&xb,
                  (void*)&use128, (void*)&farr, (void*)&rel, (void*)&out};
  (void)hipLaunchCooperativeKernel((const void*)gru_pool, dim3(256), dim3(512),
                                   args, 131072, stream);
}

// Round 12
// 1457.753 us; speedup vs baseline: 1.3807x; 1.3807x over previous
//
#include <hip/hip_runtime.h>

#define T_ 512
#define B_ 256
#define H_ 512
#define NBINS 4112  // 514 buckets x 8 subs (pooled: bin = bk*8 + (b>>5))
typedef __bf16 bf16_t;
typedef __bf16 bf16x8 __attribute__((ext_vector_type(8)));
typedef float f32x4 __attribute__((ext_vector_type(4)));

// ---------------------------------------------------------------------------
__device__ __forceinline__ float bf2f(unsigned short u) {
  unsigned x = ((unsigned)u) << 16; float f; __builtin_memcpy(&f, &x, 4); return f;
}
__device__ __forceinline__ bf16x8 pack2(f32x4 a, f32x4 b) {
  bf16x8 w;
#pragma unroll
  for (int i = 0; i < 4; ++i) { w[i] = (bf16_t)a[i]; w[i + 4] = (bf16_t)b[i]; }
  return w;
}
__device__ __forceinline__ void st_sc1(float* p, float v) {
  asm volatile("global_store_dword %0, %1, off sc0 sc1" :: "v"(p), "v"(v) : "memory");
}
__device__ __forceinline__ void st_flag(int* p, int v) {
  asm volatile("global_store_dword %0, %1, off sc0 sc1" :: "v"(p), "v"(v) : "memory");
}
__device__ __forceinline__ int ld_flag(const int* p) {
  int v;
  asm volatile("global_load_dword %0, %1, off sc0 sc1\n\ts_waitcnt vmcnt(0)"
               : "=v"(v) : "v"(p) : "memory");
  return v;
}
// 8 device-coherent 16B loads; wait INSIDE the asm (r5 lesson: issue/wait split
// across asm blocks corrupts pending regs via spills).
__device__ __forceinline__ void ld8_sc1(const float* p0, const float* p1,
                                        const float* p2, const float* p3,
                                        const float* p4, const float* p5,
                                        const float* p6, const float* p7,
                                        f32x4& v0, f32x4& v1, f32x4& v2, f32x4& v3,
                                        f32x4& v4, f32x4& v5, f32x4& v6, f32x4& v7) {
  asm volatile(
      "global_load_dwordx4 %0, %8, off sc0 sc1\n\t"
      "global_load_dwordx4 %1, %9, off sc0 sc1\n\t"
      "global_load_dwordx4 %2, %10, off sc0 sc1\n\t"
      "global_load_dwordx4 %3, %11, off sc0 sc1\n\t"
      "global_load_dwordx4 %4, %12, off sc0 sc1\n\t"
      "global_load_dwordx4 %5, %13, off sc0 sc1\n\t"
      "global_load_dwordx4 %6, %14, off sc0 sc1\n\t"
      "global_load_dwordx4 %7, %15, off sc0 sc1\n\t"
      "s_waitcnt vmcnt(0)"
      : "=&v"(v0), "=&v"(v1), "=&v"(v2), "=&v"(v3),
        "=&v"(v4), "=&v"(v5), "=&v"(v6), "=&v"(v7)
      : "v"(p0), "v"(p1), "v"(p2), "v"(p3), "v"(p4), "v"(p5), "v"(p6), "v"(p7)
      : "memory");
}
__device__ __forceinline__ float sigm(float x) { return 1.f / (1.f + __expf(-x)); }
__device__ __forceinline__ float tanh_(float a) { return 1.f - 2.f / (__expf(2.f * a) + 1.f); }

// ---------------------------------------------------------------------------
__global__ __launch_bounds__(512) void zero_meta(int* __restrict__ flags,
                                                 int* __restrict__ farr,
                                                 int* __restrict__ rel) {
  int i = threadIdx.x;
  if (i < 4) flags[i] = 0;
  if (i < 256) farr[i] = 0;
  if (i == 0) rel[0] = 0;
}

__global__ __launch_bounds__(256) void detect_resets(const void* __restrict__ rst,
                                                     int n, int* __restrict__ flags) {
  const int* pi = (const int*)rst;
  const float* pf = (const float*)rst;
  int a = 0, bq = 0, c = 0;
  int nq = n >> 2;
  for (int i = blockIdx.x * 256 + threadIdx.x; i < nq; i += gridDim.x * 256) {
    int v = pi[i];
    if (v != 0 && v != 1) a = 1;
    float f = pf[i];
    if (!(f == 0.0f || f == 1.0f)) bq = 1;
    if ((i & 1) && v != 0) c = 1;
  }
  if (a) atomicOr(&flags[0], 1);
  if (bq) atomicOr(&flags[1], 1);
  if (c) atomicOr(&flags[2], 1);
}

// Writes r8 (t-major) and r8t (b-major: r8t[b*512+t]) for streaming bins.
__global__ __launch_bounds__(256) void convert_resets(const void* __restrict__ rst,
                                                      const int* __restrict__ flags,
                                                      unsigned char* __restrict__ r8,
                                                      unsigned char* __restrict__ r8t,
                                                      int n) {
  const int* pi = (const int*)rst;
  const float* pf = (const float*)rst;
  int mode;
  if (flags[0] == 0) mode = flags[2] ? 0 : 3;  // int32 / int64
  else if (flags[1] == 0) mode = 1;            // f32
  else mode = 2;                               // bytes
  for (int i = blockIdx.x * 256 + threadIdx.x; i < n; i += gridDim.x * 256) {
    unsigned char v;
    if (mode == 0)      v = (unsigned char)(pi[i] != 0);
    else if (mode == 3) v = (unsigned char)(pi[2 * i] != 0);
    else if (mode == 1) v = (unsigned char)(pf[i] != 0.0f);
    else                v = ((const unsigned char*)rst)[i] ? 1 : 0;
    r8[i] = v;
    r8t[(i & 255) * 512 + (i >> 8)] = v;
  }
}

// Wc[koct 0..127][n 0..1535][8 bf16]: koct<64 -> Wi[koct*8+e][n]; else Wh.
__global__ __launch_bounds__(256) void build_wc(const float* __restrict__ Wi,
                                                const float* __restrict__ Wh,
                                                bf16_t* __restrict__ Wc) {
  int id = blockIdx.x * 256 + threadIdx.x;  // 0..196607
  int koct = id / 1536, n = id % 1536;
  const float* src = (koct < 64) ? Wi : Wh;
  int kk = (koct & 63) * 8;
  bf16x8 w;
#pragma unroll
  for (int e = 0; e < 8; ++e) w[e] = (bf16_t)src[(size_t)(kk + e) * 1536 + n];
  *(bf16x8*)(Wc + (size_t)id * 8) = w;
}

// bucket: p==0 -> (t==0 && !reset) ? 1 : 0; else p+1.  Pooled bin = bk*8+(b>>5).
__device__ __forceinline__ int bucket_of(int t, int rs, int& p) {
  p = (t == 0 || rs) ? 0 : p + 1;
  return (p > 0) ? (p + 1) : ((t == 0 && !rs) ? 1 : 0);
}

// Merged count + scan + scatter. 1 block x 1024 threads, 64KB dyn LDS.
// Column walks stream r8t (dword loads, 4 t's per load).
__global__ __launch_bounds__(1024) void bins_kernel(const unsigned char* __restrict__ r8t,
                                                    int* __restrict__ cur,
                                                    unsigned int* __restrict__ elem) {
  extern __shared__ int sm[];  // 2 x 8192
  int* s0 = sm;
  int* s1 = sm + 8192;
  const int tid = threadIdx.x;
  for (int i = tid; i < 8192; i += 1024) s0[i] = 0;
  __syncthreads();
  if (tid < 256) {
    int b = tid, sub = b >> 5, p = 0;
    const unsigned* rp = (const unsigned*)(r8t + b * 512);
#pragma unroll 4
    for (int tw = 0; tw < 128; ++tw) {
      unsigned v = rp[tw];
#pragma unroll
      for (int e = 0; e < 4; ++e) {
        int bk = bucket_of(tw * 4 + e, (v >> (8 * e)) & 255, p);
        atomicAdd(&s0[bk * 8 + sub], 1);
      }
    }
  }
  __syncthreads();
  int* a = s0;
  int* bb = s1;
  for (int d = 1; d < 8192; d <<= 1) {
    for (int i = tid; i < 8192; i += 1024) bb[i] = a[i] + ((i >= d) ? a[i - d] : 0);
    __syncthreads();
    int* t = a; a = bb; bb = t;
  }
  for (int i = tid; i <= NBINS; i += 1024) cur[i] = (i == 0) ? 0 : a[i - 1];
  for (int i = tid; i < 8192; i += 1024)
    bb[i] = (i == 0) ? 0 : ((i <= NBINS) ? a[i - 1] : 0);
  __syncthreads();
  if (tid < 256) {
    int b = tid, sub = b >> 5, p = 0;
    const unsigned* rp = (const unsigned*)(r8t + b * 512);
#pragma unroll 4
    for (int tw = 0; tw < 128; ++tw) {
      unsigned v = rp[tw];
#pragma unroll
      for (int e = 0; e < 4; ++e) {
        int t = tw * 4 + e;
        int bk = bucket_of(t, (v >> (8 * e)) & 255, p);
        int pos = atomicAdd(&bb[bk * 8 + sub], 1);
        elem[pos] = (unsigned)(t * B_ + b);
      }
    }
  }
}

// ---------------------------------------------------------------------------
// 3-gate MFMA core, K=512 (x-only kernel).
// ---------------------------------------------------------------------------
template <int NRGC, int LDB>
__device__ __forceinline__ void mm3(const char* lds, const char* W, int q,
                                    int rgb, int span, int nrgd, int am, int aq,
                                    f32x4 (&acc)[3][NRGC]) {
  const char* Bp = W + (size_t)(q * 16 + am) * 16;
#pragma unroll
  for (int ks = 0; ks < 16; ++ks) {
    const int koct = ks * 4 + aq;
    const char* bb = Bp + (size_t)koct * 24576;
    bf16x8 b0 = *(const bf16x8*)(bb);
    bf16x8 b1 = *(const bf16x8*)(bb + 8192);
    bf16x8 b2 = *(const bf16x8*)(bb + 16384);
#pragma unroll
    for (int rg = 0; rg < NRGC; ++rg) {
      if (rg >= rgb && rg < rgb + span && rg < nrgd) {
        const int ar = rg * 16 + am;
        bf16x8 af = *(const bf16x8*)(lds + (size_t)ar * LDB +
                                     ((koct * 16) ^ ((ar & 7) << 4)));
        acc[0][rg] = __builtin_amdgcn_mfma_f32_16x16x32_bf16(af, b0, acc[0][rg], 0, 0, 0);
        acc[1][rg] = __builtin_amdgcn_mfma_f32_16x16x32_bf16(af, b1, acc[1][rg], 0, 0, 0);
        acc[2][rg] = __builtin_amdgcn_mfma_f32_16x16x32_bf16(af, b2, acc[2][rg], 0, 0, 0);
      }
    }
  }
}

// 4-acc K=1024 core (64-row scan path, r6-proven).
template <int NKS, int NRGC, int LDB>
__device__ __forceinline__ void mm_block(const char* lds, const char* W, int q,
                                         int rgb, int span, int nrgd, int am, int aq,
                                         f32x4 (&acc)[4][NRGC]) {
  const char* Bp = W + (size_t)(q * 16 + am) * 16;
#pragma unroll
  for (int ks = 0; ks < NKS; ++ks) {
    const int koct = ks * 4 + aq;
    const char* bb = Bp + (size_t)koct * 24576;
    bf16x8 b0 = *(const bf16x8*)(bb);
    bf16x8 b1 = *(const bf16x8*)(bb + 8192);
    bf16x8 b2 = *(const bf16x8*)(bb + 16384);
#pragma unroll
    for (int rg = 0; rg < NRGC; ++rg) {
      if (rg >= rgb && rg < rgb + span && rg < nrgd) {
        const int ar = rg * 16 + am;
        bf16x8 af = *(const bf16x8*)(lds + (size_t)ar * LDB +
                                     ((koct * 16) ^ ((ar & 7) << 4)));
        acc[0][rg] = __builtin_amdgcn_mfma_f32_16x16x32_bf16(af, b0, acc[0][rg], 0, 0, 0);
        acc[1][rg] = __builtin_amdgcn_mfma_f32_16x16x32_bf16(af, b1, acc[1][rg], 0, 0, 0);
        if (ks < 16)
          acc[2][rg] = __builtin_amdgcn_mfma_f32_16x16x32_bf16(af, b2, acc[2][rg], 0, 0, 0);
        else
          acc[3][rg] = __builtin_amdgcn_mfma_f32_16x16x32_bf16(af, b2, acc[3][rg], 0, 0, 0);
      }
    }
  }
}

// ---------------------------------------------------------------------------
// x-only GEMM over ALL 131072 rows: finishes reset rows (h==0 -> out).
// ---------------------------------------------------------------------------
__global__ __launch_bounds__(512) void xonly_gemm(
    const float* __restrict__ ins, const bf16_t* __restrict__ Wic,
    const float* __restrict__ bi, const float* __restrict__ bhn,
    const unsigned char* __restrict__ r8, float* __restrict__ out) {
  extern __shared__ char lds[];
  const int u = blockIdx.x;
  const int tid = threadIdx.x, lane = tid & 63, w = tid >> 6;
  const int am = lane & 15, aq = lane >> 4;
  {  // stage 128 rows x 512 f32 -> bf16, LDB=1024, XOR-swizzled
    const int tr = tid >> 2, tl = tid & 3;
    const float* xs = ins + ((size_t)u * 128 + tr) * 512;
    const int swz = (tr & 7) << 4;
    char* lrp = lds + tr * 1024;
#pragma unroll 4
    for (int s2 = 0; s2 < 16; ++s2) {
      const int ko = tl + 4 * s2;
      f32x4 a0 = __builtin_nontemporal_load((const f32x4*)(xs + ko * 8));
      f32x4 a1 = __builtin_nontemporal_load((const f32x4*)(xs + ko * 8 + 4));
      *(bf16x8*)(lrp + ((ko * 16) ^ swz)) = pack2(a0, a1);
    }
  }
  __syncthreads();
#pragma unroll 1
  for (int s = 0; s < 4; ++s) {
    const int q = w + 8 * s;
    f32x4 acc[3][8];
#pragma unroll
    for (int gg = 0; gg < 3; ++gg)
#pragma unroll
      for (int r = 0; r < 8; ++r) acc[gg][r] = (f32x4){0.f, 0.f, 0.f, 0.f};
    mm3<8, 1024>(lds, (const char*)Wic, q, 0, 8, 8, am, aq, acc);
    const int j = q * 16 + am;
    const float bir = bi[j], biz = bi[512 + j], bin = bi[1024 + j], bh = bhn[j];
#pragma unroll
    for (int rg = 0; rg < 8; ++rg) {
#pragma unroll
      for (int qq = 0; qq < 4; ++qq) {
        const int e = u * 128 + rg * 16 + aq * 4 + qq;
        if (r8[e]) {  // reset: h==0, finished here
          float r = sigm(acc[0][rg][qq] + bir);
          float z = sigm(acc[1][rg][qq] + biz);
          float n = tanh_(acc[2][rg][qq] + bin + r * bh);
          float v = (1.f - z) * n;
          float* op = out + (size_t)e * 512 + j;
          if (e >= (T_ - 1) * B_ || r8[e + B_]) __builtin_nontemporal_store(v, op);
          else st_sc1(op, v);
        }
      }
    }
  }
}

// ---------------------------------------------------------------------------
// Pooled cooperative phase sweep (r10 body) with FLAG barrier: block stores
// farr[bid]=done (sc1, one writer per word); block 0 gathers 256 flags
// wave-wide and stores a release word; others poll the release word.
// No atomic RMW chain (r10's 256 serialized RMW/barrier was ~50us each).
// ---------------------------------------------------------------------------
__global__ __launch_bounds__(512) void gru_pool(
    const float* __restrict__ ins, const float* __restrict__ h0,
    const bf16_t* __restrict__ Wc, const float* __restrict__ bi,
    const float* __restrict__ bhn, const unsigned char* __restrict__ r8,
    const unsigned int* __restrict__ elem, const int* __restrict__ cur,
    int* __restrict__ farr, int* __restrict__ rel, float* __restrict__ out) {
  extern __shared__ char lds[];
  const int tid = threadIdx.x, lane = tid & 63, w = tid >> 6;
  const int am = lane & 15, aq = lane >> 4;
  const int nbg = gridDim.x, bg = blockIdx.x;
  int done = 0;

  for (int it = 1; it <= 513; ++it) {
    const int beg = cur[it * 8];
    const int cnt = cur[(it + 1) * 8] - beg;
    if (it >= 2 && cnt == 0) break;
    if (cnt > 0) {
      const int ntiles = (cnt + 63) >> 6;
      int lg = 0;
      while (lg < 4 && (ntiles << lg) < nbg) ++lg;
      const int nitems = ntiles << lg;
      const int Q = 32 >> lg;
      for (int i = bg; i < nitems; i += nbg) {
        const int u = i >> lg, jc = i & ((1 << lg) - 1);
        __syncthreads();
        {  // stage 64 rows x (512 x | 512 h); x nt-cached, h sc1 (waits inside)
          const int tr = tid >> 3, tl = tid & 7;
          const int row = u * 64 + tr;
          const float* xs = nullptr;
          const float* ph = nullptr;
          if (row < cnt) {
            const unsigned e = elem[beg + row];
            xs = ins + (size_t)e * 512;
            ph = (e < 256) ? (h0 + (size_t)e * 512) : (out + ((size_t)e - 256) * 512);
          }
          const int swz = (tr & 7) << 4;
          char* lrp = lds + tr * 2048;
#pragma unroll
          for (int s2 = 0; s2 < 8; ++s2) {
            const int ko = tl + 8 * s2;
            bf16x8 wv;
            if (xs) {
              f32x4 a0 = __builtin_nontemporal_load((const f32x4*)(xs + ko * 8));
              f32x4 a1 = __builtin_nontemporal_load((const f32x4*)(xs + ko * 8 + 4));
              wv = pack2(a0, a1);
            } else {
#pragma unroll
              for (int z = 0; z < 8; ++z) wv[z] = (bf16_t)0.f;
            }
            *(bf16x8*)(lrp + ((ko * 16) ^ swz)) = wv;
          }
          if (ph) {
#pragma unroll 1
            for (int hb = 0; hb < 2; ++hb) {
              f32x4 hv[8];
              const float* hp[8];
#pragma unroll
              for (int s2 = 0; s2 < 4; ++s2) {
                const int ko = tl + 8 * (8 + hb * 4 + s2);
                hp[2 * s2] = ph + (ko & 63) * 8;
                hp[2 * s2 + 1] = ph + (ko & 63) * 8 + 4;
              }
              ld8_sc1(hp[0], hp[1], hp[2], hp[3], hp[4], hp[5], hp[6], hp[7],
                      hv[0], hv[1], hv[2], hv[3], hv[4], hv[5], hv[6], hv[7]);
#pragma unroll
              for (int s2 = 0; s2 < 4; ++s2) {
                const int ko = tl + 8 * (8 + hb * 4 + s2);
                *(bf16x8*)(lrp + ((ko * 16) ^ swz)) = pack2(hv[2 * s2], hv[2 * s2 + 1]);
              }
            }
          } else {
#pragma unroll
            for (int s2 = 0; s2 < 8; ++s2) {
              const int ko = tl + 8 * (8 + s2);
              bf16x8 wv;
#pragma unroll
              for (int z = 0; z < 8; ++z) wv[z] = (bf16_t)0.f;
              *(bf16x8*)(lrp + ((ko * 16) ^ swz)) = wv;
            }
          }
        }
        __syncthreads();
        const int rem = cnt - u * 64;
        const int nrgd = ((rem < 64 ? rem : 64) + 15) >> 4;
        const int span = (Q >= 8) ? 4 : (Q >> 1);
        const int rgb = (Q >= 8) ? 0 : (w / Q) * span;
        const int nq = (Q >= 8) ? (Q >> 3) : 1;
#pragma unroll 1
        for (int s = 0; s < nq; ++s) {
          const int q = (Q >= 8) ? (jc * Q + w + 8 * s) : (jc * Q + (w & (Q - 1)));
          f32x4 acc[4][4];
#pragma unroll
          for (int gg = 0; gg < 4; ++gg)
#pragma unroll
            for (int r = 0; r < 4; ++r) acc[gg][r] = (f32x4){0.f, 0.f, 0.f, 0.f};
          mm_block<32, 4, 2048>(lds, (const char*)Wc, q, rgb, span, nrgd, am, aq, acc);
          const int j = q * 16 + am;
          const float bir = bi[j], biz = bi[512 + j], bin = bi[1024 + j], bh = bhn[j];
#pragma unroll
          for (int rg = 0; rg < 4; ++rg) {
            if (rg >= rgb && rg < rgb + span && rg < nrgd) {
#pragma unroll
              for (int qq = 0; qq < 4; ++qq) {
                const int lrow = rg * 16 + aq * 4 + qq;
                const int row = u * 64 + lrow;
                if (row < cnt) {
                  const unsigned e = elem[beg + row];
                  unsigned short hraw = *(const unsigned short*)(
                      lds + (size_t)lrow * 2048 +
                      (((64 + (j >> 3)) * 16) ^ ((lrow & 7) << 4)) + (j & 7) * 2);
                  float hp = bf2f(hraw);
                  float r = sigm(acc[0][rg][qq] + bir);
                  float z = sigm(acc[1][rg][qq] + biz);
                  float n = tanh_(acc[2][rg][qq] + bin + r * (acc[3][rg][qq] + bh));
                  float v = (1.f - z) * n + z * hp;
                  float* op = out + (size_t)e * 512 + j;
                  if (e >= (T_ - 1) * B_ || r8[e + B_]) *op = v;  // terminal: cached
                  else st_sc1(op, v);
                }
              }
            }
          }
        }
      }
    }
    // ---- flag barrier (no atomic RMW chain) ----
    __syncthreads();  // all waves' stores issued; sc1 stores are in L3 order
    ++done;
    if (tid == 0) st_flag(&farr[bg], done);
    if (bg == 0) {
      for (;;) {
        int f = (tid < nbg) ? ld_flag(&farr[tid]) : done;
        if (__syncthreads_count(f >= done) == (int)blockDim.x) break;
        __builtin_amdgcn_s_sleep(1);
      }
      if (tid == 0) st_flag(rel, done);
    }
    if (tid == 0) {
      while (ld_flag(rel) < done) __builtin_amdgcn_s_sleep(1);
    }
    __syncthreads();
  }
}

// ---------------------------------------------------------------------------
extern "C" void kernel_launch(void* const* d_in, const int* in_sizes, int n_in,
                              void* d_out, int out_size, void* d_ws, size_t ws_size,
                              hipStream_t stream) {
  const float* h0  = (const float*)d_in[0];
  const float* ins = (const float*)d_in[1];
  const float* Wi  = (const float*)d_in[2];
  const float* bi  = (const float*)d_in[3];
  const float* Wh  = (const float*)d_in[4];
  const float* bhn = (const float*)d_in[5];
  const void*  rst = d_in[6];
  float* out = (float*)d_out;

  char* ws = (char*)d_ws;
  const size_t off_r8    = 0;         // 131072
  const size_t off_r8t   = 131072;    // 131072
  const size_t off_Wc    = 262144;    // 3145728
  const size_t off_flags = 3407872;   // 64
  const size_t off_farr  = 3407936;   // 1024
  const size_t off_rel   = 3408960;   // 64
  const size_t off_cur   = 3409024;   // 16512
  const size_t off_elem  = 3425536;   // 524288
  const size_t need      = 3949824;
  if (ws_size < need) return;  // loud failure

  unsigned char* r8 = (unsigned char*)(ws + off_r8);
  unsigned char* r8t = (unsigned char*)(ws + off_r8t);
  bf16_t* Wc = (bf16_t*)(ws + off_Wc);
  int* flags = (int*)(ws + off_flags);
  int* farr = (int*)(ws + off_farr);
  int* rel = (int*)(ws + off_rel);
  int* cur = (int*)(ws + off_cur);
  unsigned int* elem = (unsigned int*)(ws + off_elem);

  zero_meta<<<1, 512, 0, stream>>>(flags, farr, rel);
  detect_resets<<<64, 256, 0, stream>>>(rst, T_ * B_, flags);
  convert_resets<<<128, 256, 0, stream>>>(rst, flags, r8, r8t, T_ * B_);
  build_wc<<<768, 256, 0, stream>>>(Wi, Wh, Wc);
  (void)hipFuncSetAttribute((const void*)bins_kernel,
                            hipFuncAttributeMaxDynamicSharedMemorySize, 65536);
  bins_kernel<<<1, 1024, 65536, stream>>>(r8t, cur, elem);

  (void)hipFuncSetAttribute((const void*)xonly_gemm,
                            hipFuncAttributeMaxDynamicSharedMemorySize, 131072);
  xonly_gemm<<<1024, 512, 131072, stream>>>(ins, Wc, bi, bhn, r8, out);

  (void)hipFuncSetAttribute((const void*)gru_pool,
                            hipFuncAttributeMaxDynamicSharedMemorySize, 131072);
  void* args[] = {(void*)&ins, (void*)&h0, (void*)&Wc, (void*)&bi, (void*)&bhn,
                  (void*)&r8, (void*)&elem, (void*)&cur, (void*)&farr,
                  (void*)&rel, (void*)&out};
  (void)hipLaunchCooperativeKernel((const void*)gru_pool, dim3(256), dim3(512),
                                   args, 131072, stream);
}